// Round 2
// baseline (292.263 us; speedup 1.0000x reference)
//
#include <hip/hip_runtime.h>
#include <stdint.h>

#define BB 16
#define NN 25200
#define CC 85
#define NCLS 80
#define KK 1000
#define KPAD 1024
#define CONF 0.25f
#define IOUT 0.45f
#define MAXWH 4096.0f
#define NW 16  // 1000 bits -> 16 u64 words

typedef unsigned long long u64;
typedef unsigned int u32;

// ---------------- kernel 1: per-anchor score + sortable key ----------------
__global__ void k_score(const float* __restrict__ x, u64* __restrict__ keys,
                        int* __restrict__ clsb) {
#pragma clang fp contract(off)
  int gid = blockIdx.x * blockDim.x + threadIdx.x;
  if (gid >= BB * NN) return;
  const float* row = x + (size_t)gid * CC;
  float obj = row[4];
  float best = -1.0f;
  int bj = 0;
  for (int c = 0; c < NCLS; ++c) {
    float p = obj * row[5 + c];
    if (p > best) { best = p; bj = c; }  // strict '>' keeps first max (argmax)
  }
  bool valid = (obj > CONF) && (best > CONF);
  float score = valid ? best : 0.0f;  // score >= 0 -> bits are order-preserving
  u32 sb = __float_as_uint(score);
  int n = gid % NN;
  u64 key = ((u64)sb << 32) | (u32)(~(u32)n);  // desc score, ties -> lower idx
  keys[gid] = key;
  clsb[gid] = bj;
}

// ---------------- kernel 2: radix-select top-1000 + bitonic sort ----------
__global__ __launch_bounds__(1024) void k_topk2(
    const u64* __restrict__ keys, u64* __restrict__ topkeys) {
  __shared__ u32 hist[256];
  __shared__ u64 buf[KPAD];
  __shared__ u64 s_prefix;
  __shared__ u32 s_k, s_cnt;
  int b = blockIdx.x;
  int tid = threadIdx.x;
  const u64* kb = keys + (size_t)b * NN;

  if (tid == 0) { s_prefix = 0ULL; s_k = KK; }
  __syncthreads();

  u64 mask = 0ULL;
  for (int pass = 0; pass < 8; ++pass) {
    int shift = 56 - 8 * pass;
    if (tid < 256) hist[tid] = 0;
    __syncthreads();
    u64 prefix = s_prefix;
    for (int n = tid; n < NN; n += 1024) {
      u64 key = kb[n];
      if ((key & mask) == prefix) {
        u32 d = (u32)(key >> shift) & 255u;
        atomicAdd(&hist[d], 1u);
      }
    }
    __syncthreads();
    if (tid == 0) {
      u32 k = s_k, cum = 0;
      int sel = 0;
      for (int d = 255; d >= 0; --d) {
        u32 h = hist[d];
        if (cum + h >= k) { sel = d; s_k = k - cum; break; }
        cum += h;
      }
      s_prefix = prefix | ((u64)sel << shift);
    }
    __syncthreads();
    mask |= (255ULL << shift);
  }

  u64 pivot = s_prefix;  // exact rank-1000 key (keys are distinct)
  if (tid == 0) s_cnt = 0;
  for (int i = tid; i < KPAD; i += 1024) buf[i] = 0ULL;
  __syncthreads();
  for (int n = tid; n < NN; n += 1024) {
    u64 key = kb[n];
    if (key >= pivot) {
      u32 pos = atomicAdd(&s_cnt, 1u);
      if (pos < KPAD) buf[pos] = key;
    }
  }
  __syncthreads();

  // bitonic sort, descending, 1024 elems / 1024 threads
  for (int k2 = 2; k2 <= KPAD; k2 <<= 1) {
    for (int j = k2 >> 1; j > 0; j >>= 1) {
      int ixj = tid ^ j;
      if (ixj > tid) {
        u64 a = buf[tid], c = buf[ixj];
        bool up = (tid & k2) == 0;  // descending blocks
        bool sw = up ? (a < c) : (a > c);
        if (sw) { buf[tid] = c; buf[ixj] = a; }
      }
      __syncthreads();
    }
  }
  topkeys[(size_t)b * KPAD + tid] = buf[tid];
}

// ---------------- kernel 3: gather boxes/cls/offbox/areas/vals -------------
__global__ __launch_bounds__(1024) void k_gather(
    const float* __restrict__ x, const int* __restrict__ clsb,
    const u64* __restrict__ topkeys, float* __restrict__ out,
    float* __restrict__ offbox, float* __restrict__ areas,
    float* __restrict__ vals) {
#pragma clang fp contract(off)
  int b = blockIdx.x;
  int tid = threadIdx.x;
  if (tid >= KK) return;
  u64 key = topkeys[(size_t)b * KPAD + tid];
  u32 ni = ~(u32)(key & 0xFFFFFFFFu);
  float val = __uint_as_float((u32)(key >> 32));
  const float* row = x + ((size_t)b * NN + ni) * CC;
  float cx = row[0], cy = row[1], w = row[2], h = row[3];
  float x1 = cx - w * 0.5f, y1 = cy - h * 0.5f;
  float x2 = cx + w * 0.5f, y2 = cy + h * 0.5f;
  float cls = (float)clsb[(size_t)b * NN + ni];
  float off = cls * MAXWH;
  float* o = out + ((size_t)b * KK + tid) * 6;
  o[0] = x1; o[1] = y1; o[2] = x2; o[3] = y2; o[5] = cls;
  float* ob = offbox + ((size_t)b * KK + tid) * 4;
  float ox1 = x1 + off, oy1 = y1 + off, ox2 = x2 + off, oy2 = y2 + off;
  ob[0] = ox1; ob[1] = oy1; ob[2] = ox2; ob[3] = oy2;
  areas[(size_t)b * KK + tid] = (ox2 - ox1) * (oy2 - oy1);
  vals[(size_t)b * KK + tid] = val;
}

// ---------------- kernel 4: suppression bitmask ----------------------------
__global__ void k_mask(const float* __restrict__ offbox,
                       const float* __restrict__ areas,
                       u64* __restrict__ mask) {
#pragma clang fp contract(off)
  int t = threadIdx.x;
  int w = t & 15;
  int r = t >> 4;
  int blk = blockIdx.x;
  int b = blk / 63;
  int i = (blk % 63) * 16 + r;
  if (i >= KK) return;
  const float* ob = offbox + (size_t)b * KK * 4;
  const float* ar = areas + (size_t)b * KK;
  float ax1 = ob[i * 4 + 0], ay1 = ob[i * 4 + 1];
  float ax2 = ob[i * 4 + 2], ay2 = ob[i * 4 + 3];
  float aa = ar[i];
  u64 bits = 0ULL;
  int j0 = w * 64;
  for (int jj = 0; jj < 64; ++jj) {
    int j = j0 + jj;
    if (j >= KK) break;
    if (j <= i) continue;
    float bx1 = ob[j * 4 + 0], by1 = ob[j * 4 + 1];
    float bx2 = ob[j * 4 + 2], by2 = ob[j * 4 + 3];
    float lx = fmaxf(ax1, bx1), ly = fmaxf(ay1, by1);
    float rx = fminf(ax2, bx2), ry = fminf(ay2, by2);
    float ww = rx - lx; ww = ww > 0.0f ? ww : 0.0f;
    float hh = ry - ly; hh = hh > 0.0f ? hh : 0.0f;
    float inter = ww * hh;
    float iou = inter / (aa + ar[j] - inter + 1e-7f);
    if (iou > IOUT) bits |= (1ULL << jj);
  }
  mask[((size_t)b * KK + i) * NW + w] = bits;
}

// ---------------- kernel 5: serial greedy scan + final score ---------------
__global__ __launch_bounds__(64) void k_scan(const u64* __restrict__ mask,
                                             const float* __restrict__ vals,
                                             float* __restrict__ out) {
  int b = blockIdx.x;
  int lane = threadIdx.x;
  const u64* mb = mask + (size_t)b * KK * NW;
  int w = lane & 15;
  u64 keep = ~0ULL;
  __shared__ u64 skeep[NW];

  u64 r0 = mb[(size_t)0 * NW + w];
  u64 r1 = mb[(size_t)1 * NW + w];
  u64 r2 = mb[(size_t)2 * NW + w];
  u64 r3 = mb[(size_t)3 * NW + w];

#define STEP(I, RV)                                                        \
  {                                                                        \
    int i_ = (I);                                                          \
    int wi_ = i_ >> 6;                                                     \
    u32 half_ = (i_ & 32) ? (u32)(keep >> 32) : (u32)keep;                 \
    u32 kw_ = (u32)__builtin_amdgcn_readlane((int)half_, wi_);             \
    u32 bit_ = (kw_ >> (i_ & 31)) & 1u;                                    \
    keep &= bit_ ? ~RV : ~0ULL;                                            \
  }

  for (int base = 0; base < KK; base += 4) {
    int p0 = base + 4 < KK ? base + 4 : KK - 1;
    int p1 = base + 5 < KK ? base + 5 : KK - 1;
    int p2 = base + 6 < KK ? base + 6 : KK - 1;
    int p3 = base + 7 < KK ? base + 7 : KK - 1;
    u64 n0 = mb[(size_t)p0 * NW + w];
    u64 n1 = mb[(size_t)p1 * NW + w];
    u64 n2 = mb[(size_t)p2 * NW + w];
    u64 n3 = mb[(size_t)p3 * NW + w];
    STEP(base + 0, r0)
    STEP(base + 1, r1)
    STEP(base + 2, r2)
    STEP(base + 3, r3)
    r0 = n0; r1 = n1; r2 = n2; r3 = n3;
  }
#undef STEP

  if (lane < NW) skeep[lane] = keep;
  __syncthreads();
  for (int s = lane; s < KK; s += 64) {
    float v = vals[(size_t)b * KK + s];
    u64 kwv = skeep[s >> 6];
    float kbit = (float)((kwv >> (s & 63)) & 1ULL);
    float fs = v * kbit * (v > CONF ? 1.0f : 0.0f);
    out[((size_t)b * KK + s) * 6 + 4] = fs;
  }
}

extern "C" void kernel_launch(void* const* d_in, const int* in_sizes, int n_in,
                              void* d_out, int out_size, void* d_ws,
                              size_t ws_size, hipStream_t stream) {
  const float* x = (const float*)d_in[0];
  float* out = (float*)d_out;
  char* ws = (char*)d_ws;

  auto align256 = [](size_t v) { return (v + 255) & ~(size_t)255; };
  size_t keys_off = 0;
  size_t keys_sz = (size_t)BB * NN * 8;                     // 3.23 MB
  size_t cls_off = align256(keys_off + keys_sz);
  size_t cls_sz = (size_t)BB * NN * 4;                      // 1.61 MB
  size_t topk_off = align256(cls_off + cls_sz);
  size_t topk_sz = (size_t)BB * KPAD * 8;                   // 128 KB
  size_t offbox_off = align256(topk_off + topk_sz);
  size_t offbox_sz = (size_t)BB * KK * 4 * 4;               // 256 KB
  size_t areas_off = align256(offbox_off + offbox_sz);
  size_t areas_sz = (size_t)BB * KK * 4;
  size_t vals_off = align256(areas_off + areas_sz);
  size_t vals_sz = (size_t)BB * KK * 4;
  size_t mask_off = keys_off;  // alias over dead key buffer (2.05 MB <= 3.23 MB)
  (void)vals_sz; (void)ws_size; (void)in_sizes; (void)n_in; (void)out_size;

  u64* keys = (u64*)(ws + keys_off);
  int* clsb = (int*)(ws + cls_off);
  u64* topkeys = (u64*)(ws + topk_off);
  float* offbox = (float*)(ws + offbox_off);
  float* areas = (float*)(ws + areas_off);
  float* vals = (float*)(ws + vals_off);
  u64* mask = (u64*)(ws + mask_off);

  k_score<<<dim3((BB * NN + 255) / 256), dim3(256), 0, stream>>>(x, keys, clsb);
  k_topk2<<<dim3(BB), dim3(1024), 0, stream>>>(keys, topkeys);
  k_gather<<<dim3(BB), dim3(1024), 0, stream>>>(x, clsb, topkeys, out, offbox,
                                                areas, vals);
  k_mask<<<dim3(BB * 63), dim3(256), 0, stream>>>(offbox, areas, mask);
  k_scan<<<dim3(BB), dim3(64), 0, stream>>>(mask, vals, out);
}